// Round 14
// baseline (149.148 us; speedup 1.0000x reference)
//
#include <hip/hip_runtime.h>
#include <math.h>

// MultiSimilarityLoss B=8192 D=128, R19: 2 launches, MFMA-free finalize.
// R18 post-mortem: symmetric (3rd attempt) dead — col-side accumulation cost
// (1M atomics, 16.9MB WRITE, butterfly VALU) > halved MFMA (never the
// bottleneck). R17 showed 2-launch works but its MFMA finalize tail cost
// 14us at 1/8 parallelism. R19: producer's general-path blocks ALREADY
// compute every same-class sim (and discard it) — store each ONCE into
// compact posbuf[row][j-class_start] via device atomicExch (coherent at L3,
// R17-proven mechanism). Pure-pos MFMA skip dropped (sims needed, ~1% work).
// Last-arrival finalize per i-strip is then PURE VALU: pb/nsum + <=160
// posbuf reads per row -> min_pos, filtered pos exp-sum, row loss. ~1-2us,
// overlapped with producer tail. k_pos eliminated.

#define B_N   8192
#define DDIM  128
#define NCLS  128
#define JSTR  32             // j-strips (grid.y), 256 j each
#define POSW  160            // posbuf slots/row (class size ~64+-8; 12 sigma)

typedef __attribute__((ext_vector_type(8))) short bf16x8;  // 8 bf16 = 4 VGPRs
typedef __attribute__((ext_vector_type(4))) float f32x4;

static constexpr float ONE_EPS  = 1.0f - 1e-5f;
static constexpr float F_MARGIN = 0.1f;
// exp in log2 domain: exp(a*s+b) = exp2(s*a*log2e + b*log2e)
static constexpr float KP2A = -2.8853900817779268f;   // -2 * log2(e)
static constexpr float KP2B =  1.4426950408889634f;   //  1 * log2(e)
static constexpr float KN2A =  57.707801635558536f;   // 40 * log2(e)
static constexpr float KN2B = -28.853900817779268f;   // -20 * log2(e)

__device__ __forceinline__ float exp2_fast(float x) {
#if __has_builtin(__builtin_amdgcn_exp2f)
    return __builtin_amdgcn_exp2f(x);
#else
    return __expf(x * 0.6931471805599453f);
#endif
}

__device__ __forceinline__ ushort rne_bf16(float f) {
    uint u = __float_as_uint(f);
    return (ushort)((u + 0x7fffu + ((u >> 16) & 1u)) >> 16);
}

// ordered-float <-> uint (monotone): atomicMax on uint == float max.
// enc of any written value != 0, so 0 == "never written" => -inf.
__device__ __forceinline__ unsigned enc_f(float f) {
    unsigned u = __float_as_uint(f);
    return (u & 0x80000000u) ? ~u : (u | 0x80000000u);
}
__device__ __forceinline__ float dec_f(unsigned e) {
    return (e & 0x80000000u) ? __uint_as_float(e ^ 0x80000000u)
                             : __uint_as_float(~e);
}

// fb tiled layout: [tile=row>>4][ks 0..3][q 0..3][c=row&15][8 elems].
// A wave fragment load (fixed ks; lanes (q,c)) is one contiguous 1KB.
__device__ __forceinline__ int fbt_off(int row, int ks, int q) {
    return (((row >> 4) * 16 + ks * 4 + q) * 16 + (row & 15)) * 8;
}

// ---------------------------------------------------------------- K1: prep
__global__ __launch_bounds__(256)
void k_prep(const float* __restrict__ feats, const int* __restrict__ labels,
            ushort* __restrict__ fb, int* __restrict__ plab,
            int* __restrict__ cstart_g, unsigned* __restrict__ maxenc,
            float* __restrict__ nsum, int* __restrict__ cnt,
            float* __restrict__ out)
{
    __shared__ int cnts[NCLS], pre[NCLS], scn[NCLS], lcur[NCLS];
    __shared__ int sdst[256];
    const int t = threadIdx.x, b = blockIdx.x, r0 = b * 256;

    if (t < NCLS) { cnts[t] = 0; pre[t] = 0; }
    __syncthreads();
    for (int idx = t; idx < B_N / 4; idx += 256) {
        const int4 L = ((const int4*)labels)[idx];
        atomicAdd(&cnts[L.x], 1); atomicAdd(&cnts[L.y], 1);
        atomicAdd(&cnts[L.z], 1); atomicAdd(&cnts[L.w], 1);
        if (idx * 4 < r0) {
            atomicAdd(&pre[L.x], 1); atomicAdd(&pre[L.y], 1);
            atomicAdd(&pre[L.z], 1); atomicAdd(&pre[L.w], 1);
        }
    }
    __syncthreads();
    if (t < NCLS) scn[t] = cnts[t];
    __syncthreads();
    #pragma unroll
    for (int off = 1; off < NCLS; off <<= 1) {     // Hillis-Steele inclusive scan
        int v = 0;
        if (t < NCLS && t >= off) v = scn[t - off];
        __syncthreads();
        if (t < NCLS) scn[t] += v;
        __syncthreads();
    }
    if (t < NCLS) {
        const int cs = scn[t] - cnts[t];           // exclusive start
        lcur[t] = cs + pre[t];
        if (b == 0) cstart_g[t] = cs;
    }
    if (b == 0 && t == 0) { cstart_g[NCLS] = B_N; *out = 0.f; }
    // zero-init accumulators (each block its 256-row slice) + strip counter
    maxenc[r0 + t] = 0u;
    nsum[r0 + t]   = 0.f;
    if (t == 0) cnt[b] = 0;
    __syncthreads();

    const int myl = labels[r0 + t];
    const int dst = atomicAdd(&lcur[myl], 1);      // within-class order irrelevant
    plab[dst] = myl;
    sdst[t] = dst;
    __syncthreads();

    // permute + cast fp32->bf16 into tiled layout
    for (int m = 0; m < 32; ++m) {
        const int rowl = m * 8 + (t >> 5), ch = t & 31;
        float4 v = *(const float4*)(feats + (size_t)(r0 + rowl) * DDIM + ch * 4);
        ushort4 o;
        o.x = rne_bf16(v.x); o.y = rne_bf16(v.y);
        o.z = rne_bf16(v.z); o.w = rne_bf16(v.w);
        const int d = sdst[rowl];
        const int k = ch * 4;
        const int off = (((d >> 4) * 16 + (k >> 5) * 4 + ((k >> 3) & 3)) * 16
                         + (d & 15)) * 8 + (k & 7);
        *(ushort4*)(fb + off) = o;
    }
}

// ---------------------------------------------------------------- K2: neg pass + posbuf store + VALU finalize
__global__ __launch_bounds__(256, 3)
void k_main(const ushort* __restrict__ fb, const int* __restrict__ plab,
            const int* __restrict__ cstart_g, unsigned* __restrict__ maxenc,
            float* __restrict__ nsum, float* __restrict__ posbuf,
            int* __restrict__ cnt, float* __restrict__ out)
{
    __shared__ float wsum[4];
    __shared__ int   slast;
    const int t = threadIdx.x, w = t >> 6, lane = t & 63, q = lane >> 4, cl = lane & 15;
    const int bx = blockIdx.x, by = blockIdx.y;
    const int iw0 = bx * 256 + w * 64;
    const int j0  = by * 256;

    // exact disjointness from sorted labels (wave-uniform scalar loads)
    const int lif  = plab[bx * 256], lil = plab[bx * 256 + 255];
    const int ljf0 = plab[j0],       ljl0 = plab[j0 + 255];
    const bool fast = (lil < ljf0) || (ljl0 < lif);

    bf16x8 ifr[4][4];
    #pragma unroll
    for (int g = 0; g < 4; ++g) {
        const int row = iw0 + g * 16 + cl;
        #pragma unroll
        for (int ks = 0; ks < 4; ++ks)
            ifr[g][ks] = *(const bf16x8*)(fb + fbt_off(row, ks, q));
    }

    float vmax[4], ns[4];
    #pragma unroll
    for (int g = 0; g < 4; ++g) { vmax[g] = -INFINITY; ns[g] = 0.f; }

    bf16x8 jfr[4];
    #pragma unroll
    for (int ks = 0; ks < 4; ++ks)
        jfr[ks] = *(const bf16x8*)(fb + fbt_off(j0 + cl, ks, q));

    if (fast) {
        // ---------- fast path: every pair guaranteed different label ----------
        #pragma unroll 1
        for (int jt = 0; jt < 16; ++jt) {
            f32x4 acc[4];
            #pragma unroll
            for (int g = 0; g < 4; ++g) {
                acc[g] = f32x4{0.f, 0.f, 0.f, 0.f};
                #pragma unroll
                for (int ks = 0; ks < 4; ++ks)
                    acc[g] = __builtin_amdgcn_mfma_f32_16x16x32_bf16(jfr[ks], ifr[g][ks], acc[g], 0, 0, 0);
            }
            if (jt < 15) {
                const int jb = j0 + (jt + 1) * 16;
                #pragma unroll
                for (int ks = 0; ks < 4; ++ks)
                    jfr[ks] = *(const bf16x8*)(fb + fbt_off(jb + cl, ks, q));
            }
            #pragma unroll
            for (int g = 0; g < 4; ++g) {
                vmax[g] = fmaxf(vmax[g], fmaxf(fmaxf(acc[g][0], acc[g][1]),
                                               fmaxf(acc[g][2], acc[g][3])));
                const float e0 = exp2_fast(fmaf(acc[g][0], KN2A, KN2B));
                const float e1 = exp2_fast(fmaf(acc[g][1], KN2A, KN2B));
                const float e2 = exp2_fast(fmaf(acc[g][2], KN2A, KN2B));
                const float e3 = exp2_fast(fmaf(acc[g][3], KN2A, KN2B));
                ns[g] += (e0 + e1) + (e2 + e3);
            }
        }
    } else {
        // ---------- general path: same-class sims stored to posbuf ----------
        int li[4], glf[4], gll[4], cbase[4];
        #pragma unroll
        for (int g = 0; g < 4; ++g) {
            li[g]    = plab[iw0 + g * 16 + cl];
            glf[g]   = plab[iw0 + g * 16];
            gll[g]   = plab[iw0 + g * 16 + 15];
            cbase[g] = cstart_g[li[g]];
        }
        int ljf = plab[j0], ljl = plab[j0 + 15];

        #pragma unroll 1
        for (int jt = 0; jt < 16; ++jt) {
            const int jb = j0 + jt * 16;
            bool pn[4];
            bool anyS = false;
            #pragma unroll
            for (int g = 0; g < 4; ++g) {
                pn[g] = (gll[g] < ljf) || (ljl < glf[g]);   // label-disjoint tile
                anyS = anyS || !pn[g];
            }
            int4 lj = {0, 0, 0, 0};
            if (anyS) lj = *(const int4*)(plab + jb + q * 4);

            f32x4 acc[4];
            #pragma unroll
            for (int g = 0; g < 4; ++g) {
                acc[g] = f32x4{0.f, 0.f, 0.f, 0.f};
                #pragma unroll
                for (int ks = 0; ks < 4; ++ks)
                    acc[g] = __builtin_amdgcn_mfma_f32_16x16x32_bf16(jfr[ks], ifr[g][ks], acc[g], 0, 0, 0);
            }
            if (jt < 15) {
                #pragma unroll
                for (int ks = 0; ks < 4; ++ks)
                    jfr[ks] = *(const bf16x8*)(fb + fbt_off(jb + 16 + cl, ks, q));
                ljf = plab[jb + 16]; ljl = plab[jb + 31];
            }
            #pragma unroll
            for (int g = 0; g < 4; ++g) {
                if (pn[g]) {
                    vmax[g] = fmaxf(vmax[g], fmaxf(fmaxf(acc[g][0], acc[g][1]),
                                                   fmaxf(acc[g][2], acc[g][3])));
                    const float e0 = exp2_fast(fmaf(acc[g][0], KN2A, KN2B));
                    const float e1 = exp2_fast(fmaf(acc[g][1], KN2A, KN2B));
                    const float e2 = exp2_fast(fmaf(acc[g][2], KN2A, KN2B));
                    const float e3 = exp2_fast(fmaf(acc[g][3], KN2A, KN2B));
                    ns[g] += (e0 + e1) + (e2 + e3);
                } else {
                    const int row = iw0 + g * 16 + cl;
                    #pragma unroll
                    for (int r = 0; r < 4; ++r) {
                        const float sv = acc[g][r];
                        const int ljr = (r == 0) ? lj.x : (r == 1) ? lj.y : (r == 2) ? lj.z : lj.w;
                        if (li[g] == ljr) {
                            const int jl = jb + q * 4 + r - cbase[g];
                            if ((unsigned)jl < POSW)     // device-scope store -> L3
                                atomicExch(&posbuf[(size_t)row * POSW + jl], sv);
                        } else {
                            vmax[g] = fmaxf(vmax[g], sv);
                            ns[g] += exp2_fast(fmaf(sv, KN2A, KN2B));
                        }
                    }
                }
            }
        }
    }

    // ---- i-side reduce + atomic accumulate (R17-proven)
    #pragma unroll
    for (int g = 0; g < 4; ++g) {
        vmax[g] = fmaxf(vmax[g], __shfl_xor(vmax[g], 16, 64));
        vmax[g] = fmaxf(vmax[g], __shfl_xor(vmax[g], 32, 64));
        ns[g]  += __shfl_xor(ns[g], 16, 64);
        ns[g]  += __shfl_xor(ns[g], 32, 64);
    }
    if (q == 0) {
        #pragma unroll
        for (int g = 0; g < 4; ++g) {
            const int row = iw0 + g * 16 + cl;
            atomicMax(&maxenc[row], enc_f(vmax[g]));
            atomicAdd(&nsum[row], ns[g]);
        }
    }

    // ======================= last-arrival VALU finalize =====================
    __syncthreads();                               // drains vmcnt: atomics done
    if (t == 0) slast = (atomicAdd(&cnt[bx], 1) == JSTR - 1);
    __syncthreads();
    if (!slast) return;

    // per-thread row; all stats via atomic reads (coherent point)
    const int row = bx * 256 + t;
    const int l   = plab[row];
    const int cs  = cstart_g[l];
    int ncl = cstart_g[l + 1] - cs;
    if (ncl > POSW) ncl = POSW;
    const unsigned menc = atomicAdd(&maxenc[row], 0u);
    const float    nsv  = atomicAdd(&nsum[row], 0.f);
    const float mx = (menc != 0u) ? dec_f(menc) : -INFINITY;
    const float pb = fminf(ONE_EPS, mx + F_MARGIN);

    float* pbase = &posbuf[(size_t)row * POSW];
    float ps = 0.f, vmin = INFINITY;
    int k = 0;
    for (; k + 8 <= ncl; k += 8) {                 // 8 atomic reads in flight
        float v[8];
        #pragma unroll
        for (int u = 0; u < 8; ++u) v[u] = atomicAdd(pbase + k + u, 0.f);
        #pragma unroll
        for (int u = 0; u < 8; ++u) {
            const float sv = v[u];
            vmin = fminf(vmin, sv < ONE_EPS ? sv : INFINITY);
            ps += (sv < pb) ? exp2_fast(fmaf(sv, KP2A, KP2B)) : 0.f;
        }
    }
    for (; k < ncl; ++k) {
        const float sv = atomicAdd(pbase + k, 0.f);
        vmin = fminf(vmin, sv < ONE_EPS ? sv : INFINITY);
        ps += (sv < pb) ? exp2_fast(fmaf(sv, KP2A, KP2B)) : 0.f;
    }
    // valid: has_neg (pb>-inf), any(pos_mask) (ps>0),
    //        any(neg_mask)&has_pos (pb > min_pos; false if min_pos=inf)
    float rl = (pb > -INFINITY && ps > 0.f && pb > vmin)
             ? log1pf(ps) * 0.5f + log1pf(nsv) * 0.025f : 0.f;   // /2, /40

    #pragma unroll
    for (int off = 32; off > 0; off >>= 1) rl += __shfl_down(rl, off, 64);
    if (lane == 0) wsum[w] = rl;
    __syncthreads();
    if (t == 0)
        atomicAdd(out, (wsum[0] + wsum[1] + wsum[2] + wsum[3]) * (1.0f / (float)B_N));
}

// ---------------------------------------------------------------- launch
extern "C" void kernel_launch(void* const* d_in, const int* in_sizes, int n_in,
                              void* d_out, int out_size, void* d_ws, size_t ws_size,
                              hipStream_t stream)
{
    const float* feats  = (const float*)d_in[0];
    const int*   labels = (const int*)d_in[1];

    char* p = (char*)d_ws;
    ushort*   fb     = (ushort*)p;   p += (size_t)B_N * DDIM * 2;   // 2 MB tiled bf16
    float*    posbuf = (float*)p;    p += (size_t)B_N * POSW * 4;   // 5.24 MB
    unsigned* maxenc = (unsigned*)p; p += (size_t)B_N * 4;          // 32 KB
    float*    nsum   = (float*)p;    p += (size_t)B_N * 4;          // 32 KB
    int*      plab   = (int*)p;      p += (size_t)B_N * 4;          // 32 KB
    int*      cstart = (int*)p;      p += 132 * 4;
    int*      cnt    = (int*)p;      p += 32 * 4;                   // strip counters
    float*    out    = (float*)d_out;

    k_prep<<<32, 256, 0, stream>>>(feats, labels, fb, plab, cstart,
                                   maxenc, nsum, cnt, out);
    k_main<<<dim3(32, JSTR), 256, 0, stream>>>(fb, plab, cstart, maxenc, nsum,
                                               posbuf, cnt, out);
}

// Round 15
// 100.803 us; speedup vs baseline: 1.4796x; 1.4796x over previous
//
#include <hip/hip_runtime.h>
#include <math.h>

// MultiSimilarityLoss B=8192 D=128, R20 = exact restore of the R11 champion
// (100.8us, best of 19 rounds).
// Meta-ledger: R11's 3-launch structure beat every alternative tried:
//   symmetric (R12/R18: accumulation cost > halved MFMA — MFMA never the
//   bottleneck), fence-based fusion (R8/R14/R15: device __threadfence per
//   block = L2 writeback on 8-XCD chip), atomic-based fusion (R17: 14us
//   serialized finalize tail; R19: 1M scattered atomics = 29MB HBM writeback),
//   LDS j-staging (R16: barrier lockstep > L2 saving).
// Fixed costs in the timed region: ~42us workspace-poison fill + ~2us/gap;
// kernels are ~52us of the 100.8. Structure locked.
// Components: k_prep (counting-sort by label + fp32->bf16 cast into
// fragment-tiled fb so every MFMA fragment load is one contiguous 1KB);
// k_neg ((256,3) => ~170-reg budget, zero spill; grid 32x32; far blocks
// run a branch-free pure-negative loop with register j-prefetch; partials
// to plain per-(jstrip,row) arrays — no atomics); k_pos (128 class blocks:
// fold partials -> pb, class-diagonal min_pos + filtered pos exp-sum, loss).

#define B_N  8192
#define DDIM 128
#define NCLS 128
#define JSTR 32              // j-strips (grid.y), 256 j each

typedef __attribute__((ext_vector_type(8))) short bf16x8;  // 8 bf16 = 4 VGPRs
typedef __attribute__((ext_vector_type(4))) float f32x4;

static constexpr float ONE_EPS  = 1.0f - 1e-5f;
static constexpr float F_MARGIN = 0.1f;
// exp in log2 domain: exp(a*s+b) = exp2(s*a*log2e + b*log2e)
static constexpr float KP2A = -2.8853900817779268f;   // -2 * log2(e)
static constexpr float KP2B =  1.4426950408889634f;   //  1 * log2(e)
static constexpr float KN2A =  57.707801635558536f;   // 40 * log2(e)
static constexpr float KN2B = -28.853900817779268f;   // -20 * log2(e)

__device__ __forceinline__ float exp2_fast(float x) {
#if __has_builtin(__builtin_amdgcn_exp2f)
    return __builtin_amdgcn_exp2f(x);
#else
    return __expf(x * 0.6931471805599453f);
#endif
}

__device__ __forceinline__ ushort rne_bf16(float f) {
    uint u = __float_as_uint(f);
    return (ushort)((u + 0x7fffu + ((u >> 16) & 1u)) >> 16);
}

// fb tiled layout: [tile=row>>4][ks 0..3][q 0..3][c=row&15][8 elems].
// A wave fragment load (fixed ks; lanes (q,c)) is one contiguous 1KB.
__device__ __forceinline__ int fbt_off(int row, int ks, int q) {
    return (((row >> 4) * 16 + ks * 4 + q) * 16 + (row & 15)) * 8;
}

// ---------------------------------------------------------------- K1: prep
__global__ __launch_bounds__(256)
void k_prep(const float* __restrict__ feats, const int* __restrict__ labels,
            ushort* __restrict__ fb, int* __restrict__ plab,
            int* __restrict__ cstart_g, float* __restrict__ out)
{
    __shared__ int cnt[NCLS], pre[NCLS], scn[NCLS], lcur[NCLS];
    __shared__ int sdst[256];
    const int t = threadIdx.x, b = blockIdx.x, r0 = b * 256;

    if (t < NCLS) { cnt[t] = 0; pre[t] = 0; }
    __syncthreads();
    // full histogram + prefix (rows < r0) histogram; r0 % 4 == 0 so int4-aligned
    for (int idx = t; idx < B_N / 4; idx += 256) {
        const int4 L = ((const int4*)labels)[idx];
        atomicAdd(&cnt[L.x], 1); atomicAdd(&cnt[L.y], 1);
        atomicAdd(&cnt[L.z], 1); atomicAdd(&cnt[L.w], 1);
        if (idx * 4 < r0) {
            atomicAdd(&pre[L.x], 1); atomicAdd(&pre[L.y], 1);
            atomicAdd(&pre[L.z], 1); atomicAdd(&pre[L.w], 1);
        }
    }
    __syncthreads();
    if (t < NCLS) scn[t] = cnt[t];
    __syncthreads();
    #pragma unroll
    for (int off = 1; off < NCLS; off <<= 1) {     // Hillis-Steele inclusive scan
        int v = 0;
        if (t < NCLS && t >= off) v = scn[t - off];
        __syncthreads();
        if (t < NCLS) scn[t] += v;
        __syncthreads();
    }
    if (t < NCLS) {
        const int cs = scn[t] - cnt[t];            // exclusive start
        lcur[t] = cs + pre[t];
        if (b == 0) cstart_g[t] = cs;
    }
    if (b == 0 && t == 0) { cstart_g[NCLS] = B_N; *out = 0.f; }
    __syncthreads();

    const int myl = labels[r0 + t];
    const int dst = atomicAdd(&lcur[myl], 1);      // within-class order irrelevant
    plab[dst] = myl;
    sdst[t] = dst;
    __syncthreads();

    // permute + cast fp32->bf16 into tiled layout
    for (int m = 0; m < 32; ++m) {
        const int rowl = m * 8 + (t >> 5), ch = t & 31;
        float4 v = *(const float4*)(feats + (size_t)(r0 + rowl) * DDIM + ch * 4);
        ushort4 o;
        o.x = rne_bf16(v.x); o.y = rne_bf16(v.y);
        o.z = rne_bf16(v.z); o.w = rne_bf16(v.w);
        const int d = sdst[rowl];
        const int k = ch * 4;
        const int off = (((d >> 4) * 16 + (k >> 5) * 4 + ((k >> 3) & 3)) * 16
                         + (d & 15)) * 8 + (k & 7);
        *(ushort4*)(fb + off) = o;
    }
}

// ---------------------------------------------------------------- K2: full pass, neg max + unfiltered neg exp-sum
__global__ __launch_bounds__(256, 3)
void k_neg(const ushort* __restrict__ fb, const int* __restrict__ plab,
           float* __restrict__ maxn_part, float* __restrict__ nsum_part)
{
    const int t = threadIdx.x, w = t >> 6, lane = t & 63, q = lane >> 4, cl = lane & 15;
    const int bx = blockIdx.x, by = blockIdx.y;
    const int iw0 = bx * 256 + w * 64;
    const int j0  = by * 256;

    bf16x8 ifr[4][4];
    #pragma unroll
    for (int g = 0; g < 4; ++g) {
        const int row = iw0 + g * 16 + cl;
        #pragma unroll
        for (int ks = 0; ks < 4; ++ks)
            ifr[g][ks] = *(const bf16x8*)(fb + fbt_off(row, ks, q));
    }

    float vmax[4], ns[4];
    #pragma unroll
    for (int g = 0; g < 4; ++g) { vmax[g] = -INFINITY; ns[g] = 0.f; }

    bf16x8 jfr[4];
    #pragma unroll
    for (int ks = 0; ks < 4; ++ks)
        jfr[ks] = *(const bf16x8*)(fb + fbt_off(j0 + cl, ks, q));

    if (bx > by + 1 || by > bx + 1) {
        // ---------- fast path: every pair guaranteed different label ----------
        #pragma unroll 1
        for (int jt = 0; jt < 16; ++jt) {
            f32x4 acc[4];
            #pragma unroll
            for (int g = 0; g < 4; ++g) {
                acc[g] = f32x4{0.f, 0.f, 0.f, 0.f};
                #pragma unroll
                for (int ks = 0; ks < 4; ++ks)
                    acc[g] = __builtin_amdgcn_mfma_f32_16x16x32_bf16(jfr[ks], ifr[g][ks], acc[g], 0, 0, 0);
            }
            if (jt < 15) {
                const int jb = j0 + (jt + 1) * 16;
                #pragma unroll
                for (int ks = 0; ks < 4; ++ks)
                    jfr[ks] = *(const bf16x8*)(fb + fbt_off(jb + cl, ks, q));
            }
            #pragma unroll
            for (int g = 0; g < 4; ++g) {
                vmax[g] = fmaxf(vmax[g], fmaxf(fmaxf(acc[g][0], acc[g][1]),
                                               fmaxf(acc[g][2], acc[g][3])));
                const float e0 = exp2_fast(fmaf(acc[g][0], KN2A, KN2B));
                const float e1 = exp2_fast(fmaf(acc[g][1], KN2A, KN2B));
                const float e2 = exp2_fast(fmaf(acc[g][2], KN2A, KN2B));
                const float e3 = exp2_fast(fmaf(acc[g][3], KN2A, KN2B));
                ns[g] += (e0 + e1) + (e2 + e3);
            }
        }
    } else {
        // ---------- general path: near-diagonal blocks ----------
        int li[4], glf[4], gll[4];
        #pragma unroll
        for (int g = 0; g < 4; ++g) {
            li[g]  = plab[iw0 + g * 16 + cl];
            glf[g] = plab[iw0 + g * 16];
            gll[g] = plab[iw0 + g * 16 + 15];
        }
        int ljf = plab[j0], ljl = plab[j0 + 15];

        #pragma unroll 1
        for (int jt = 0; jt < 16; ++jt) {
            const int jb = j0 + jt * 16;
            bool pn[4], pp[4];
            bool anyMixed = false;
            #pragma unroll
            for (int g = 0; g < 4; ++g) {
                pn[g] = (gll[g] < ljf) || (ljl < glf[g]);                       // disjoint
                pp[g] = (glf[g] == gll[g]) && (ljf == ljl) && (glf[g] == ljf);  // one class
                anyMixed = anyMixed || (!pn[g] && !pp[g]);
            }
            int4 lj = {0, 0, 0, 0};
            if (anyMixed) lj = *(const int4*)(plab + jb + q * 4);

            f32x4 acc[4];
            #pragma unroll
            for (int g = 0; g < 4; ++g) {
                acc[g] = f32x4{0.f, 0.f, 0.f, 0.f};
                if (!pp[g]) {                        // pure-pos tile: nothing to do
                    #pragma unroll
                    for (int ks = 0; ks < 4; ++ks)
                        acc[g] = __builtin_amdgcn_mfma_f32_16x16x32_bf16(jfr[ks], ifr[g][ks], acc[g], 0, 0, 0);
                }
            }
            if (jt < 15) {
                #pragma unroll
                for (int ks = 0; ks < 4; ++ks)
                    jfr[ks] = *(const bf16x8*)(fb + fbt_off(jb + 16 + cl, ks, q));
                ljf = plab[jb + 16]; ljl = plab[jb + 31];
            }
            #pragma unroll
            for (int g = 0; g < 4; ++g) {
                if (pn[g]) {
                    vmax[g] = fmaxf(vmax[g], fmaxf(fmaxf(acc[g][0], acc[g][1]),
                                                   fmaxf(acc[g][2], acc[g][3])));
                    const float e0 = exp2_fast(fmaf(acc[g][0], KN2A, KN2B));
                    const float e1 = exp2_fast(fmaf(acc[g][1], KN2A, KN2B));
                    const float e2 = exp2_fast(fmaf(acc[g][2], KN2A, KN2B));
                    const float e3 = exp2_fast(fmaf(acc[g][3], KN2A, KN2B));
                    ns[g] += (e0 + e1) + (e2 + e3);
                } else if (!pp[g]) {                 // mixed tile
                    #pragma unroll
                    for (int r = 0; r < 4; ++r) {
                        const float sv = acc[g][r];
                        const int ljr = (r == 0) ? lj.x : (r == 1) ? lj.y : (r == 2) ? lj.z : lj.w;
                        const bool same = (li[g] == ljr);
                        vmax[g] = fmaxf(vmax[g], same ? -INFINITY : sv);
                        const float ev = exp2_fast(fmaf(sv, KN2A, KN2B));
                        ns[g] += same ? 0.f : ev;
                    }
                }
            }
        }
    }

    #pragma unroll
    for (int g = 0; g < 4; ++g) {
        vmax[g] = fmaxf(vmax[g], __shfl_xor(vmax[g], 16, 64));
        vmax[g] = fmaxf(vmax[g], __shfl_xor(vmax[g], 32, 64));
        ns[g]  += __shfl_xor(ns[g], 16, 64);
        ns[g]  += __shfl_xor(ns[g], 32, 64);
    }
    if (q == 0) {
        #pragma unroll
        for (int g = 0; g < 4; ++g) {
            const int row = iw0 + g * 16 + cl;
            maxn_part[by * B_N + row] = vmax[g];
            nsum_part[by * B_N + row] = ns[g];
        }
    }
}

// ---------------------------------------------------------------- K3: fold + diagonal (min_pos, pos sum) + loss
__global__ __launch_bounds__(256)
void k_pos(const ushort* __restrict__ fb, const int* __restrict__ cstart_g,
           const float* __restrict__ maxn_part, const float* __restrict__ nsum_part,
           float* __restrict__ out)
{
    __shared__ float spb[256], sns[256];
    __shared__ float bsum;
    const int c = blockIdx.x, t = threadIdx.x;
    const int w = t >> 6, lane = t & 63, q = lane >> 4, cl = lane & 15;
    const int s = cstart_g[c], e = cstart_g[c + 1], n = e - s;
    if (t == 0) bsum = 0.f;

    // fold j-strip partials for this class's rows
    for (int r = t; r < n && r < 256; r += 256) {
        float mx = -INFINITY, nsum = 0.f;
        #pragma unroll 4
        for (int js = 0; js < JSTR; ++js) {
            mx    = fmaxf(mx, maxn_part[js * B_N + s + r]);
            nsum += nsum_part[js * B_N + s + r];
        }
        spb[r] = fminf(ONE_EPS, mx + F_MARGIN);   // -inf if no negatives
        sns[r] = nsum;
    }
    __syncthreads();

    if (n > 0) {
        const int nt = (n + 15) >> 4;
        for (int it = w; it < nt; it += 4) {
            const int il = it * 16 + cl;
            bf16x8 ifr[4];
            #pragma unroll
            for (int ks = 0; ks < 4; ++ks)
                ifr[ks] = *(const bf16x8*)(fb + fbt_off(s + it * 16 + cl, ks, q));
            const float pbl = (il < n) ? spb[il] : -INFINITY;
            float ps = 0.f, vmin = INFINITY;
            for (int jt = 0; jt < nt; ++jt) {
                bf16x8 jfr[4];
                #pragma unroll
                for (int ks = 0; ks < 4; ++ks)
                    jfr[ks] = *(const bf16x8*)(fb + fbt_off(s + jt * 16 + cl, ks, q));
                f32x4 acc = {0.f, 0.f, 0.f, 0.f};
                #pragma unroll
                for (int ks = 0; ks < 4; ++ks)
                    acc = __builtin_amdgcn_mfma_f32_16x16x32_bf16(jfr[ks], ifr[ks], acc, 0, 0, 0);
                #pragma unroll
                for (int r = 0; r < 4; ++r) {
                    const int jl = jt * 16 + q * 4 + r;
                    const float sv = acc[r];
                    const bool inb = (jl < n);
                    vmin = fminf(vmin, (inb && sv < ONE_EPS) ? sv : INFINITY);
                    const float ev = exp2_fast(fmaf(sv, KP2A, KP2B));
                    ps += (inb && sv < pbl) ? ev : 0.f;
                }
            }
            ps  += __shfl_xor(ps, 16, 64);
            ps  += __shfl_xor(ps, 32, 64);
            vmin = fminf(vmin, __shfl_xor(vmin, 16, 64));
            vmin = fminf(vmin, __shfl_xor(vmin, 32, 64));
            float rl = 0.f;
            if (q == 0 && il < n) {
                const float pbv = spb[il], nsv = sns[il];
                // valid: has_neg (pb>-inf), any(pos_mask) (ps>0),
                //        any(neg_mask) & has_pos (pb > min_pos; false if min_pos=inf)
                if (pbv > -INFINITY && ps > 0.f && pbv > vmin)
                    rl = log1pf(ps) * 0.5f + log1pf(nsv) * 0.025f;  // /2, /40
            }
            #pragma unroll
            for (int off = 32; off > 0; off >>= 1) rl += __shfl_down(rl, off, 64);
            if (lane == 0) atomicAdd(&bsum, rl);
        }
    }
    __syncthreads();
    if (t == 0) atomicAdd(out, bsum * (1.0f / (float)B_N));
}

// ---------------------------------------------------------------- launch
extern "C" void kernel_launch(void* const* d_in, const int* in_sizes, int n_in,
                              void* d_out, int out_size, void* d_ws, size_t ws_size,
                              hipStream_t stream)
{
    const float* feats  = (const float*)d_in[0];
    const int*   labels = (const int*)d_in[1];

    char* p = (char*)d_ws;
    ushort* fb        = (ushort*)p;  p += (size_t)B_N * DDIM * 2;   // 2 MB tiled bf16
    float*  maxn_part = (float*)p;   p += (size_t)JSTR * B_N * 4;   // 1 MB
    float*  nsum_part = (float*)p;   p += (size_t)JSTR * B_N * 4;   // 1 MB
    int*    plab      = (int*)p;     p += (size_t)B_N * 4;          // 32 KB
    int*    cstart    = (int*)p;     p += 132 * 4;
    float*  out       = (float*)d_out;

    k_prep<<<32, 256, 0, stream>>>(feats, labels, fb, plab, cstart, out);
    k_neg<<<dim3(32, JSTR), 256, 0, stream>>>(fb, plab, maxn_part, nsum_part);
    k_pos<<<NCLS, 256, 0, stream>>>(fb, cstart, maxn_part, nsum_part, out);
}